// Round 8
// baseline (386.457 us; speedup 1.0000x reference)
//
#include <hip/hip_runtime.h>
#include <stdint.h>

typedef unsigned short ushort_t;
typedef __attribute__((ext_vector_type(8))) short bf16x8;   // 8 bf16 in 4 VGPRs
typedef __attribute__((ext_vector_type(4))) float f32x4;

// ---------- helpers ----------
__device__ __forceinline__ unsigned short f2b(float f) {
  unsigned u = __float_as_uint(f);
  u += 0x7fffu + ((u >> 16) & 1u);   // round-to-nearest-even
  return (unsigned short)(u >> 16);
}

__device__ __forceinline__ void async16(const void* g, void* l) {
  __builtin_amdgcn_global_load_lds(
      (const __attribute__((address_space(1))) void*)g,
      (__attribute__((address_space(3))) void*)l, 16, 0, 0);
}

// ---------- LayerNorm (fp32 in -> bf16 out), one block per row, C=1024 ----------
__global__ __launch_bounds__(256) void ln_kernel(
    const float* __restrict__ x, const float* __restrict__ g,
    const float* __restrict__ be, ushort_t* __restrict__ out) {
  const int C = 1024;
  int row = blockIdx.x;
  const float4* xr = (const float4*)(x + (size_t)row * C);
  int tid = threadIdx.x;
  float4 v = xr[tid];
  float s = v.x + v.y + v.z + v.w;
  float sq = v.x * v.x + v.y * v.y + v.z * v.z + v.w * v.w;
  #pragma unroll
  for (int off = 32; off > 0; off >>= 1) {
    s += __shfl_xor(s, off);
    sq += __shfl_xor(sq, off);
  }
  __shared__ float ss[4], ssq[4];
  int wv = tid >> 6;
  if ((tid & 63) == 0) { ss[wv] = s; ssq[wv] = sq; }
  __syncthreads();
  s = ss[0] + ss[1] + ss[2] + ss[3];
  sq = ssq[0] + ssq[1] + ssq[2] + ssq[3];
  float mu = s * (1.f / C);
  float var = sq * (1.f / C) - mu * mu;
  float rs = rsqrtf(var + 1e-5f);
  float4 gv = ((const float4*)g)[tid];
  float4 bv = ((const float4*)be)[tid];
  ushort4 o;
  o.x = f2b((v.x - mu) * rs * gv.x + bv.x);
  o.y = f2b((v.y - mu) * rs * gv.y + bv.y);
  o.z = f2b((v.z - mu) * rs * gv.z + bv.z);
  o.w = f2b((v.w - mu) * rs * gv.w + bv.w);
  ((ushort4*)(out + (size_t)row * C))[tid] = o;
}

// ---------- batched transpose + fp32->bf16 cast: in (bz,R,Cin) -> out (bz,Cin,R) ----------
__global__ __launch_bounds__(256) void transpose_cast_kernel(
    const float* __restrict__ in, ushort_t* __restrict__ out, int R, int Cin) {
  __shared__ float tile[32][33];
  int bz = blockIdx.z;
  in += (size_t)bz * R * Cin;
  out += (size_t)bz * R * Cin;
  int c0 = blockIdx.x * 32, r0 = blockIdx.y * 32;
  int tx = threadIdx.x, ty = threadIdx.y;
  #pragma unroll
  for (int i = 0; i < 4; i++)
    tile[ty + 8 * i][tx] = in[(size_t)(r0 + ty + 8 * i) * Cin + c0 + tx];
  __syncthreads();
  #pragma unroll
  for (int i = 0; i < 4; i++)
    out[(size_t)(c0 + ty + 8 * i) * R + r0 + tx] = f2b(tile[tx][ty + 8 * i]);
}

// ---------- V transpose: QKV (4096,3072) bf16 -> Vt (B*H, 64, 2048) bf16 ----------
__global__ __launch_bounds__(256) void transpose_v_kernel(
    const ushort_t* __restrict__ qkv, ushort_t* __restrict__ vt) {
  __shared__ ushort_t tile[32][33];
  int bh = blockIdx.z;
  int b = bh >> 4, h = bh & 15;
  int d0 = blockIdx.x * 32, t0 = blockIdx.y * 32;
  int tx = threadIdx.x, ty = threadIdx.y;
  #pragma unroll
  for (int i = 0; i < 4; i++)
    tile[ty + 8 * i][tx] =
        qkv[(size_t)(b * 2048 + t0 + ty + 8 * i) * 3072 + 2048 + h * 64 + d0 + tx];
  __syncthreads();
  #pragma unroll
  for (int i = 0; i < 4; i++)
    vt[(size_t)(bh * 64 + d0 + ty + 8 * i) * 2048 + t0 + tx] = tile[tx][ty + 8 * i];
}

// ---------- GEMM: out(M,N) = A(M,K) @ Bt(N,K)^T, bf16 in, dbuf staging ----------
// MT: M-tile (128 or 64). FLAGS: 1=relu, 2=bf16 out, 4=+bias, 8=+resid.
// Double-buffered LDS: ONE barrier per K-step; next chunk's global_load_lds
// flies during current chunk's MFMAs (critical at 1-2 blocks/CU).
template <int MT, int N, int K, int FLAGS>
__global__ __launch_bounds__(256, 2) void gemm_bt_kernel(
    const ushort_t* __restrict__ A, const ushort_t* __restrict__ Bt,
    const float* __restrict__ bias, const float* __restrict__ resid,
    void* __restrict__ outv) {
  constexpr int MI = MT / 32;            // acc row-tiles per wave (4 or 2)
  __shared__ ushort_t Als[2][MT * 32];
  __shared__ ushort_t Bls[2][128 * 32];
  int tid = threadIdx.x, w = tid >> 6, lane = tid & 63, quad = lane >> 4, l16 = lane & 15;
  int bn0 = blockIdx.x * 128, bm0 = blockIdx.y * MT;
  int wm = (w >> 1) * (MT / 2), wn = (w & 1) * 64;
  f32x4 acc[MI][4];
  #pragma unroll
  for (int i = 0; i < MI; i++)
    #pragma unroll
    for (int j = 0; j < 4; j++) acc[i][j] = f32x4{0.f, 0.f, 0.f, 0.f};
  const ushort_t* Ag = A + (size_t)bm0 * K;
  const ushort_t* Bg = Bt + (size_t)bn0 * K;
  int lr = lane >> 2, lco = (lane & 3) * 8;
  auto stage = [&](int k0, int bi) {
    if constexpr (MT == 128) {
      async16(Ag + (size_t)(w * 32 + lr) * K + k0 + lco, &Als[bi][w * 1024]);
      async16(Ag + (size_t)(w * 32 + 16 + lr) * K + k0 + lco, &Als[bi][w * 1024 + 512]);
    } else {
      async16(Ag + (size_t)(w * 16 + lr) * K + k0 + lco, &Als[bi][w * 512]);
    }
    async16(Bg + (size_t)(w * 32 + lr) * K + k0 + lco, &Bls[bi][w * 1024]);
    async16(Bg + (size_t)(w * 32 + 16 + lr) * K + k0 + lco, &Bls[bi][w * 1024 + 512]);
  };
  stage(0, 0);
  int s = 0;
  for (int k0 = 0; k0 < K; k0 += 32, s ^= 1) {
    __syncthreads();                      // chunk k0 staged; prior buf's reads done
    if (k0 + 32 < K) stage(k0 + 32, s ^ 1);
    bf16x8 af[MI], bf[4];
    #pragma unroll
    for (int i = 0; i < MI; i++)
      af[i] = *(const bf16x8*)&Als[s][(wm + i * 16 + l16) * 32 + quad * 8];
    #pragma unroll
    for (int j = 0; j < 4; j++)
      bf[j] = *(const bf16x8*)&Bls[s][(wn + j * 16 + l16) * 32 + quad * 8];
    #pragma unroll
    for (int i = 0; i < MI; i++)
      #pragma unroll
      for (int j = 0; j < 4; j++)
        acc[i][j] = __builtin_amdgcn_mfma_f32_16x16x32_bf16(af[i], bf[j], acc[i][j], 0, 0, 0);
  }
  #pragma unroll
  for (int i = 0; i < MI; i++)
    #pragma unroll
    for (int j = 0; j < 4; j++)
      #pragma unroll
      for (int r = 0; r < 4; r++) {
        int row = bm0 + wm + i * 16 + quad * 4 + r;
        int col = bn0 + wn + j * 16 + l16;
        float v = acc[i][j][r];
        if constexpr (FLAGS & 4) v += bias[col];
        if constexpr (FLAGS & 8) v += resid[(size_t)row * N + col];
        if constexpr (FLAGS & 1) v = fmaxf(v, 0.f);
        if constexpr ((FLAGS & 2) != 0)
          ((ushort_t*)outv)[(size_t)row * N + col] = f2b(v);
        else
          ((float*)outv)[(size_t)row * N + col] = v;
      }
}

// ---------- causal flash attention: dbuf LDS staging + S^T softmax ----------
// 1024 blocks = 32 (b,h) x 32 q-blocks of 64 rows -> 4 blocks/CU.
// Wave w owns the single 16-row q-subtile w. One barrier per 64-key chunk;
// chunk k+1's global_load_lds flies during chunk k's compute. Softmax in exp2
// domain, lane = q-row (S^T form); P B-frags via shuffle build.
__global__ __launch_bounds__(256, 4) void attn_kernel(
    const ushort_t* __restrict__ qkv, const ushort_t* __restrict__ vt,
    ushort_t* __restrict__ out) {
  const int T = 2048, CC = 3072;
  __shared__ ushort_t Kls[2][2 * 64 * 32];
  __shared__ ushort_t Vls[2][2 * 64 * 32];
  int fid = blockIdx.x;                       // 1024
  int bh = (fid & 7) * 4 + ((fid >> 3) & 3);  // XCD swizzle: 4 heads per XCD
  int qb = 31 - (fid >> 5);                   // longest q-blocks first
  int b = bh >> 4, h = bh & 15;
  int q0 = qb * 64;
  int tid = threadIdx.x, w = tid >> 6, lane = tid & 63, quad = lane >> 4, l16 = lane & 15;
  int srow = w * 16 + (lane >> 2);
  int sco = (lane & 3) * 8;
  const ushort_t* kg = qkv + (size_t)(b * T + srow) * CC + 1024 + h * 64 + sco;
  const ushort_t* vg = vt + (size_t)(bh * 64 + srow) * T + sco;
  int q0s = q0 + w * 16;
  int trow = q0s + l16;
  const ushort_t* qp = qkv + (size_t)(b * T + trow) * CC + h * 64 + quad * 8;
  bf16x8 aq[2] = { *(const bf16x8*)qp, *(const bf16x8*)(qp + 32) };
  f32x4 O[4];
  #pragma unroll
  for (int i = 0; i < 4; i++) O[i] = f32x4{0.f, 0.f, 0.f, 0.f};
  float mrun = -1e30f, lrun = 0.f;
  const float ksc = 0.03125f * 1.44269504f;  // C^-0.5 * log2(e)
  int src0 = (quad & 1) * 32 + l16;
  int src1 = src0 + 16;
  bool hiq = quad >= 2;
  auto stage = [&](int kb, int bi) {
    int s0 = kb * 64;
    async16(kg + (size_t)s0 * CC, &Kls[bi][w * 512]);
    async16(kg + (size_t)s0 * CC + 32, &Kls[bi][2048 + w * 512]);
    async16(vg + s0, &Vls[bi][w * 512]);
    async16(vg + s0 + 32, &Vls[bi][2048 + w * 512]);
  };
  stage(0, 0);
  for (int kb = 0; kb <= qb; kb++) {
    __syncthreads();
    if (kb < qb) stage(kb + 1, (kb + 1) & 1);
    int bi = kb & 1;
    int s0 = kb * 64;
    bf16x8 kfr[4][2], vfr[4][2];
    #pragma unroll
    for (int t = 0; t < 4; t++)
      #pragma unroll
      for (int ks = 0; ks < 2; ks++) {
        kfr[t][ks] = *(const bf16x8*)&Kls[bi][(ks * 64 + t * 16 + l16) * 32 + quad * 8];
        vfr[t][ks] = *(const bf16x8*)&Vls[bi][(ks * 64 + t * 16 + l16) * 32 + quad * 8];
      }
    f32x4 st[4];
    #pragma unroll
    for (int t = 0; t < 4; t++) {
      st[t] = f32x4{0.f, 0.f, 0.f, 0.f};
      #pragma unroll
      for (int ks = 0; ks < 2; ks++)
        st[t] = __builtin_amdgcn_mfma_f32_16x16x32_bf16(kfr[t][ks], aq[ks], st[t], 0, 0, 0);
    }
    float sv[4][4];
    float vmax = -1e30f;
    if (kb == qb) {
      #pragma unroll
      for (int t = 0; t < 4; t++)
        #pragma unroll
        for (int r = 0; r < 4; r++) {
          float sc = st[t][r] * ksc;
          int scol = s0 + t * 16 + quad * 4 + r;
          if (scol > trow) sc = -1e30f;
          sv[t][r] = sc;
          vmax = fmaxf(vmax, sc);
        }
    } else {
      #pragma unroll
      for (int t = 0; t < 4; t++)
        #pragma unroll
        for (int r = 0; r < 4; r++) {
          float sc = st[t][r] * ksc;
          sv[t][r] = sc;
          vmax = fmaxf(vmax, sc);
        }
    }
    vmax = fmaxf(vmax, __shfl_xor(vmax, 16));
    vmax = fmaxf(vmax, __shfl_xor(vmax, 32));
    float mnew = fmaxf(mrun, vmax);
    float alpha = __builtin_amdgcn_exp2f(mrun - mnew);
    mrun = mnew;
    float psum = 0.f;
    int pk[4][2];
    #pragma unroll
    for (int t = 0; t < 4; t++) {
      float p0 = __builtin_amdgcn_exp2f(sv[t][0] - mnew);
      float p1 = __builtin_amdgcn_exp2f(sv[t][1] - mnew);
      float p2 = __builtin_amdgcn_exp2f(sv[t][2] - mnew);
      float p3 = __builtin_amdgcn_exp2f(sv[t][3] - mnew);
      psum += (p0 + p1) + (p2 + p3);
      pk[t][0] = (int)((unsigned)f2b(p0) | ((unsigned)f2b(p1) << 16));
      pk[t][1] = (int)((unsigned)f2b(p2) | ((unsigned)f2b(p3) << 16));
    }
    psum += __shfl_xor(psum, 16);
    psum += __shfl_xor(psum, 32);
    lrun = lrun * alpha + psum;
    #pragma unroll
    for (int dt = 0; dt < 4; dt++) O[dt] *= alpha;
    #pragma unroll
    for (int g32 = 0; g32 < 2; g32++) {
      int t0 = 2 * g32, t1 = t0 + 1;
      int a0 = __shfl(pk[t0][0], src0), b0 = __shfl(pk[t1][0], src0);
      int a1 = __shfl(pk[t0][1], src0), b1 = __shfl(pk[t1][1], src0);
      int a2 = __shfl(pk[t0][0], src1), b2 = __shfl(pk[t1][0], src1);
      int a3 = __shfl(pk[t0][1], src1), b3 = __shfl(pk[t1][1], src1);
      union { int4 i; bf16x8 h; } u;
      u.i.x = hiq ? b0 : a0;
      u.i.y = hiq ? b1 : a1;
      u.i.z = hiq ? b2 : a2;
      u.i.w = hiq ? b3 : a3;
      #pragma unroll
      for (int dt = 0; dt < 4; dt++)
        O[dt] = __builtin_amdgcn_mfma_f32_16x16x32_bf16(vfr[dt][g32], u.h, O[dt], 0, 0, 0);
    }
  }
  float inv = 1.f / lrun;
  #pragma unroll
  for (int dt = 0; dt < 4; dt++) {
    ushort4 o;
    unsigned short* op = (unsigned short*)&o;
    #pragma unroll
    for (int r = 0; r < 4; r++) op[r] = f2b(O[dt][r] * inv);
    *(ushort4*)&out[(size_t)(b * T + trow) * 1024 + h * 64 + dt * 16 + quad * 4] = o;
  }
}

// ---------- host ----------
extern "C" void kernel_launch(void* const* d_in, const int* in_sizes, int n_in,
                              void* d_out, int out_size, void* d_ws, size_t ws_size,
                              hipStream_t stream) {
  const int B = 2, T = 2048, C = 1024, H = 16, D = 64, FF = 4096;
  const int M = B * T;  // 4096
  const float* x   = (const float*)d_in[0];
  const float* Wq  = (const float*)d_in[1];
  const float* Wk  = (const float*)d_in[2];
  const float* Wv  = (const float*)d_in[3];
  const float* Wo  = (const float*)d_in[4];
  const float* bo  = (const float*)d_in[5];
  const float* W1  = (const float*)d_in[6];
  const float* b1  = (const float*)d_in[7];
  const float* W2  = (const float*)d_in[8];
  const float* b2  = (const float*)d_in[9];
  const float* g1  = (const float*)d_in[10];
  const float* be1 = (const float*)d_in[11];
  const float* g2  = (const float*)d_in[12];
  const float* be2 = (const float*)d_in[13];
  float* out = (float*)d_out;

  char* ws = (char*)d_ws;
  size_t off = 0;
  auto alloc = [&](size_t bytes) {
    void* p = ws + off;
    off += (bytes + 255) & ~(size_t)255;
    return p;
  };
  ushort_t* qkvt = (ushort_t*)alloc((size_t)3 * C * C * 2);
  ushort_t* wot  = (ushort_t*)alloc((size_t)C * C * 2);
  ushort_t* w1t  = (ushort_t*)alloc((size_t)FF * C * 2);
  ushort_t* w2t  = (ushort_t*)alloc((size_t)C * FF * 2);
  ushort_t* hbuf = (ushort_t*)alloc((size_t)M * C * 2);
  ushort_t* big  = (ushort_t*)alloc((size_t)M * FF * 2);
  ushort_t* vtb  = (ushort_t*)alloc((size_t)M * C * 2);
  ushort_t* aout = (ushort_t*)alloc((size_t)M * C * 2);
  float*    x2   = (float*)alloc((size_t)M * C * 4);

  dim3 tb(32, 8);
  transpose_cast_kernel<<<dim3(D / 32, C / 32, H), tb, 0, stream>>>(Wq, qkvt, C, D);
  transpose_cast_kernel<<<dim3(D / 32, C / 32, H), tb, 0, stream>>>(Wk, qkvt + (size_t)C * C, C, D);
  transpose_cast_kernel<<<dim3(D / 32, C / 32, H), tb, 0, stream>>>(Wv, qkvt + (size_t)2 * C * C, C, D);
  transpose_cast_kernel<<<dim3(C / 32, C / 32, 1), tb, 0, stream>>>(Wo, wot, C, C);
  transpose_cast_kernel<<<dim3(FF / 32, C / 32, 1), tb, 0, stream>>>(W1, w1t, C, FF);
  transpose_cast_kernel<<<dim3(C / 32, FF / 32, 1), tb, 0, stream>>>(W2, w2t, FF, C);
  ln_kernel<<<M, 256, 0, stream>>>(x, g1, be1, hbuf);
  // QKV = h @ Wqkv^T -> bf16
  gemm_bt_kernel<128, 3072, 1024, 2><<<dim3(24, 32), 256, 0, stream>>>(
      hbuf, qkvt, nullptr, nullptr, big);
  transpose_v_kernel<<<dim3(2, T / 32, B * H), tb, 0, stream>>>(big, vtb);
  attn_kernel<<<1024, 256, 0, stream>>>(big, vtb, aout);
  // x2 = attn @ Wo^T + bo + x (fp32)  [MT=64 -> 512 blocks, 2/CU]
  gemm_bt_kernel<64, 1024, 1024, 4 | 8><<<dim3(8, 64), 256, 0, stream>>>(
      aout, wot, bo, x, x2);
  ln_kernel<<<M, 256, 0, stream>>>(x2, g2, be2, hbuf);
  // ff1 = relu(h2 @ W1^T + b1) -> bf16
  gemm_bt_kernel<128, 4096, 1024, 1 | 2 | 4><<<dim3(32, 32), 256, 0, stream>>>(
      hbuf, w1t, b1, nullptr, big);
  // out = ff1 @ W2^T + b2 + x2 (fp32)  [MT=64 -> 512 blocks, 2/CU]
  gemm_bt_kernel<64, 1024, 4096, 4 | 8><<<dim3(8, 64), 256, 0, stream>>>(
      big, w2t, b2, x2, out);
}

// Round 9
// 380.928 us; speedup vs baseline: 1.0145x; 1.0145x over previous
//
#include <hip/hip_runtime.h>
#include <stdint.h>

typedef unsigned short ushort_t;
typedef __attribute__((ext_vector_type(8))) short bf16x8;   // 8 bf16 in 4 VGPRs
typedef __attribute__((ext_vector_type(4))) float f32x4;

// ---------- helpers ----------
__device__ __forceinline__ unsigned short f2b(float f) {
  unsigned u = __float_as_uint(f);
  u += 0x7fffu + ((u >> 16) & 1u);   // round-to-nearest-even
  return (unsigned short)(u >> 16);
}

__device__ __forceinline__ void async16(const void* g, void* l) {
  __builtin_amdgcn_global_load_lds(
      (const __attribute__((address_space(1))) void*)g,
      (__attribute__((address_space(3))) void*)l, 16, 0, 0);
}

// ---------- LayerNorm (fp32 in -> bf16 out), one block per row, C=1024 ----------
__global__ __launch_bounds__(256) void ln_kernel(
    const float* __restrict__ x, const float* __restrict__ g,
    const float* __restrict__ be, ushort_t* __restrict__ out) {
  const int C = 1024;
  int row = blockIdx.x;
  const float4* xr = (const float4*)(x + (size_t)row * C);
  int tid = threadIdx.x;
  float4 v = xr[tid];
  float s = v.x + v.y + v.z + v.w;
  float sq = v.x * v.x + v.y * v.y + v.z * v.z + v.w * v.w;
  #pragma unroll
  for (int off = 32; off > 0; off >>= 1) {
    s += __shfl_xor(s, off);
    sq += __shfl_xor(sq, off);
  }
  __shared__ float ss[4], ssq[4];
  int wv = tid >> 6;
  if ((tid & 63) == 0) { ss[wv] = s; ssq[wv] = sq; }
  __syncthreads();
  s = ss[0] + ss[1] + ss[2] + ss[3];
  sq = ssq[0] + ssq[1] + ssq[2] + ssq[3];
  float mu = s * (1.f / C);
  float var = sq * (1.f / C) - mu * mu;
  float rs = rsqrtf(var + 1e-5f);
  float4 gv = ((const float4*)g)[tid];
  float4 bv = ((const float4*)be)[tid];
  ushort4 o;
  o.x = f2b((v.x - mu) * rs * gv.x + bv.x);
  o.y = f2b((v.y - mu) * rs * gv.y + bv.y);
  o.z = f2b((v.z - mu) * rs * gv.z + bv.z);
  o.w = f2b((v.w - mu) * rs * gv.w + bv.w);
  ((ushort4*)(out + (size_t)row * C))[tid] = o;
}

// ---------- split-K final reduce: out = p0 + p1 + bias + resid (fp32), N=1024 ----------
__global__ __launch_bounds__(256) void reduce2_kernel(
    const float* __restrict__ p0, const float* __restrict__ p1,
    const float* __restrict__ bias, const float* __restrict__ resid,
    float* __restrict__ out) {
  int idx = blockIdx.x * 256 + threadIdx.x;      // float4 index
  float4 a = ((const float4*)p0)[idx];
  float4 b = ((const float4*)p1)[idx];
  float4 r = ((const float4*)resid)[idx];
  float4 bi = ((const float4*)bias)[idx & 255];  // 1024 floats = 256 float4 per row
  float4 o;
  o.x = a.x + b.x + r.x + bi.x;
  o.y = a.y + b.y + r.y + bi.y;
  o.z = a.z + b.z + r.z + bi.z;
  o.w = a.w + b.w + r.w + bi.w;
  ((float4*)out)[idx] = o;
}

// ---------- batched transpose + fp32->bf16 cast: in (bz,R,Cin) -> out (bz,Cin,R) ----------
__global__ __launch_bounds__(256) void transpose_cast_kernel(
    const float* __restrict__ in, ushort_t* __restrict__ out, int R, int Cin) {
  __shared__ float tile[32][33];
  int bz = blockIdx.z;
  in += (size_t)bz * R * Cin;
  out += (size_t)bz * R * Cin;
  int c0 = blockIdx.x * 32, r0 = blockIdx.y * 32;
  int tx = threadIdx.x, ty = threadIdx.y;
  #pragma unroll
  for (int i = 0; i < 4; i++)
    tile[ty + 8 * i][tx] = in[(size_t)(r0 + ty + 8 * i) * Cin + c0 + tx];
  __syncthreads();
  #pragma unroll
  for (int i = 0; i < 4; i++)
    out[(size_t)(c0 + ty + 8 * i) * R + r0 + tx] = f2b(tile[tx][ty + 8 * i]);
}

// ---------- V transpose: QKV (4096,3072) bf16 -> Vt (B*H, 64, 2048) bf16 ----------
__global__ __launch_bounds__(256) void transpose_v_kernel(
    const ushort_t* __restrict__ qkv, ushort_t* __restrict__ vt) {
  __shared__ ushort_t tile[32][33];
  int bh = blockIdx.z;
  int b = bh >> 4, h = bh & 15;
  int d0 = blockIdx.x * 32, t0 = blockIdx.y * 32;
  int tx = threadIdx.x, ty = threadIdx.y;
  #pragma unroll
  for (int i = 0; i < 4; i++)
    tile[ty + 8 * i][tx] =
        qkv[(size_t)(b * 2048 + t0 + ty + 8 * i) * 3072 + 2048 + h * 64 + d0 + tx];
  __syncthreads();
  #pragma unroll
  for (int i = 0; i < 4; i++)
    vt[(size_t)(bh * 64 + d0 + ty + 8 * i) * 2048 + t0 + tx] = tile[tx][ty + 8 * i];
}

// ---------- GEMM: out(M,N) = A(M,K) @ Bt(N,K)^T, bf16 in, 128x128 tile, dbuf ----------
// FLAGS: 1=relu, 2=bf16 out, 4=+bias, 8=+resid. SK: split-K factor (1 or 2).
// SK=2: blockIdx.z selects K-half; raw fp32 partials to pp0/pp1 (reduce later).
template <int N, int K, int FLAGS, int SK>
__global__ __launch_bounds__(256, 2) void gemm_bt_kernel(
    const ushort_t* __restrict__ A, const ushort_t* __restrict__ Bt,
    const float* __restrict__ bias, const float* __restrict__ resid,
    void* __restrict__ outv, float* __restrict__ pp0, float* __restrict__ pp1) {
  constexpr int KS = K / SK;             // K-span per block
  __shared__ ushort_t Als[2][128 * 32];
  __shared__ ushort_t Bls[2][128 * 32];
  int tid = threadIdx.x, w = tid >> 6, lane = tid & 63, quad = lane >> 4, l16 = lane & 15;
  int bn0 = blockIdx.x * 128, bm0 = blockIdx.y * 128;
  int koff = (SK > 1) ? blockIdx.z * KS : 0;
  int wm = (w >> 1) * 64, wn = (w & 1) * 64;
  f32x4 acc[4][4];
  #pragma unroll
  for (int i = 0; i < 4; i++)
    #pragma unroll
    for (int j = 0; j < 4; j++) acc[i][j] = f32x4{0.f, 0.f, 0.f, 0.f};
  const ushort_t* Ag = A + (size_t)bm0 * K + koff;
  const ushort_t* Bg = Bt + (size_t)bn0 * K + koff;
  int lr = lane >> 2, lco = (lane & 3) * 8;
  auto stage = [&](int k0, int bi) {
    async16(Ag + (size_t)(w * 32 + lr) * K + k0 + lco, &Als[bi][w * 1024]);
    async16(Ag + (size_t)(w * 32 + 16 + lr) * K + k0 + lco, &Als[bi][w * 1024 + 512]);
    async16(Bg + (size_t)(w * 32 + lr) * K + k0 + lco, &Bls[bi][w * 1024]);
    async16(Bg + (size_t)(w * 32 + 16 + lr) * K + k0 + lco, &Bls[bi][w * 1024 + 512]);
  };
  stage(0, 0);
  int s = 0;
  for (int k0 = 0; k0 < KS; k0 += 32, s ^= 1) {
    __syncthreads();
    if (k0 + 32 < KS) stage(k0 + 32, s ^ 1);
    bf16x8 af[4], bf[4];
    #pragma unroll
    for (int i = 0; i < 4; i++)
      af[i] = *(const bf16x8*)&Als[s][(wm + i * 16 + l16) * 32 + quad * 8];
    #pragma unroll
    for (int j = 0; j < 4; j++)
      bf[j] = *(const bf16x8*)&Bls[s][(wn + j * 16 + l16) * 32 + quad * 8];
    #pragma unroll
    for (int i = 0; i < 4; i++)
      #pragma unroll
      for (int j = 0; j < 4; j++)
        acc[i][j] = __builtin_amdgcn_mfma_f32_16x16x32_bf16(af[i], bf[j], acc[i][j], 0, 0, 0);
  }
  float* pdst = nullptr;
  if constexpr (SK > 1) pdst = blockIdx.z ? pp1 : pp0;
  #pragma unroll
  for (int i = 0; i < 4; i++)
    #pragma unroll
    for (int j = 0; j < 4; j++)
      #pragma unroll
      for (int r = 0; r < 4; r++) {
        int row = bm0 + wm + i * 16 + quad * 4 + r;
        int col = bn0 + wn + j * 16 + l16;
        float v = acc[i][j][r];
        if constexpr (SK > 1) {
          pdst[(size_t)row * N + col] = v;   // raw partial
        } else {
          if constexpr (FLAGS & 4) v += bias[col];
          if constexpr (FLAGS & 8) v += resid[(size_t)row * N + col];
          if constexpr (FLAGS & 1) v = fmaxf(v, 0.f);
          if constexpr ((FLAGS & 2) != 0)
            ((ushort_t*)outv)[(size_t)row * N + col] = f2b(v);
          else
            ((float*)outv)[(size_t)row * N + col] = v;
        }
      }
}

// ---------- causal flash attention: dbuf LDS staging + S^T softmax ----------
// 1024 blocks = 32 (b,h) x 32 q-blocks of 64 rows -> 4 blocks/CU.
__global__ __launch_bounds__(256, 4) void attn_kernel(
    const ushort_t* __restrict__ qkv, const ushort_t* __restrict__ vt,
    ushort_t* __restrict__ out) {
  const int T = 2048, CC = 3072;
  __shared__ ushort_t Kls[2][2 * 64 * 32];
  __shared__ ushort_t Vls[2][2 * 64 * 32];
  int fid = blockIdx.x;                       // 1024
  int bh = (fid & 7) * 4 + ((fid >> 3) & 3);  // XCD swizzle: 4 heads per XCD
  int qb = 31 - (fid >> 5);                   // longest q-blocks first
  int b = bh >> 4, h = bh & 15;
  int q0 = qb * 64;
  int tid = threadIdx.x, w = tid >> 6, lane = tid & 63, quad = lane >> 4, l16 = lane & 15;
  int srow = w * 16 + (lane >> 2);
  int sco = (lane & 3) * 8;
  const ushort_t* kg = qkv + (size_t)(b * T + srow) * CC + 1024 + h * 64 + sco;
  const ushort_t* vg = vt + (size_t)(bh * 64 + srow) * T + sco;
  int q0s = q0 + w * 16;
  int trow = q0s + l16;
  const ushort_t* qp = qkv + (size_t)(b * T + trow) * CC + h * 64 + quad * 8;
  bf16x8 aq[2] = { *(const bf16x8*)qp, *(const bf16x8*)(qp + 32) };
  f32x4 O[4];
  #pragma unroll
  for (int i = 0; i < 4; i++) O[i] = f32x4{0.f, 0.f, 0.f, 0.f};
  float mrun = -1e30f, lrun = 0.f;
  const float ksc = 0.03125f * 1.44269504f;  // C^-0.5 * log2(e)
  int src0 = (quad & 1) * 32 + l16;
  int src1 = src0 + 16;
  bool hiq = quad >= 2;
  auto stage = [&](int kb, int bi) {
    int s0 = kb * 64;
    async16(kg + (size_t)s0 * CC, &Kls[bi][w * 512]);
    async16(kg + (size_t)s0 * CC + 32, &Kls[bi][2048 + w * 512]);
    async16(vg + s0, &Vls[bi][w * 512]);
    async16(vg + s0 + 32, &Vls[bi][2048 + w * 512]);
  };
  stage(0, 0);
  for (int kb = 0; kb <= qb; kb++) {
    __syncthreads();
    if (kb < qb) stage(kb + 1, (kb + 1) & 1);
    int bi = kb & 1;
    int s0 = kb * 64;
    bf16x8 kfr[4][2], vfr[4][2];
    #pragma unroll
    for (int t = 0; t < 4; t++)
      #pragma unroll
      for (int ks = 0; ks < 2; ks++) {
        kfr[t][ks] = *(const bf16x8*)&Kls[bi][(ks * 64 + t * 16 + l16) * 32 + quad * 8];
        vfr[t][ks] = *(const bf16x8*)&Vls[bi][(ks * 64 + t * 16 + l16) * 32 + quad * 8];
      }
    f32x4 st[4];
    #pragma unroll
    for (int t = 0; t < 4; t++) {
      st[t] = f32x4{0.f, 0.f, 0.f, 0.f};
      #pragma unroll
      for (int ks = 0; ks < 2; ks++)
        st[t] = __builtin_amdgcn_mfma_f32_16x16x32_bf16(kfr[t][ks], aq[ks], st[t], 0, 0, 0);
    }
    float sv[4][4];
    float vmax = -1e30f;
    if (kb == qb) {
      #pragma unroll
      for (int t = 0; t < 4; t++)
        #pragma unroll
        for (int r = 0; r < 4; r++) {
          float sc = st[t][r] * ksc;
          int scol = s0 + t * 16 + quad * 4 + r;
          if (scol > trow) sc = -1e30f;
          sv[t][r] = sc;
          vmax = fmaxf(vmax, sc);
        }
    } else {
      #pragma unroll
      for (int t = 0; t < 4; t++)
        #pragma unroll
        for (int r = 0; r < 4; r++) {
          float sc = st[t][r] * ksc;
          sv[t][r] = sc;
          vmax = fmaxf(vmax, sc);
        }
    }
    vmax = fmaxf(vmax, __shfl_xor(vmax, 16));
    vmax = fmaxf(vmax, __shfl_xor(vmax, 32));
    float mnew = fmaxf(mrun, vmax);
    float alpha = __builtin_amdgcn_exp2f(mrun - mnew);
    mrun = mnew;
    float psum = 0.f;
    int pk[4][2];
    #pragma unroll
    for (int t = 0; t < 4; t++) {
      float p0 = __builtin_amdgcn_exp2f(sv[t][0] - mnew);
      float p1 = __builtin_amdgcn_exp2f(sv[t][1] - mnew);
      float p2 = __builtin_amdgcn_exp2f(sv[t][2] - mnew);
      float p3 = __builtin_amdgcn_exp2f(sv[t][3] - mnew);
      psum += (p0 + p1) + (p2 + p3);
      pk[t][0] = (int)((unsigned)f2b(p0) | ((unsigned)f2b(p1) << 16));
      pk[t][1] = (int)((unsigned)f2b(p2) | ((unsigned)f2b(p3) << 16));
    }
    psum += __shfl_xor(psum, 16);
    psum += __shfl_xor(psum, 32);
    lrun = lrun * alpha + psum;
    #pragma unroll
    for (int dt = 0; dt < 4; dt++) O[dt] *= alpha;
    #pragma unroll
    for (int g32 = 0; g32 < 2; g32++) {
      int t0 = 2 * g32, t1 = t0 + 1;
      int a0 = __shfl(pk[t0][0], src0), b0 = __shfl(pk[t1][0], src0);
      int a1 = __shfl(pk[t0][1], src0), b1 = __shfl(pk[t1][1], src0);
      int a2 = __shfl(pk[t0][0], src1), b2 = __shfl(pk[t1][0], src1);
      int a3 = __shfl(pk[t0][1], src1), b3 = __shfl(pk[t1][1], src1);
      union { int4 i; bf16x8 h; } u;
      u.i.x = hiq ? b0 : a0;
      u.i.y = hiq ? b1 : a1;
      u.i.z = hiq ? b2 : a2;
      u.i.w = hiq ? b3 : a3;
      #pragma unroll
      for (int dt = 0; dt < 4; dt++)
        O[dt] = __builtin_amdgcn_mfma_f32_16x16x32_bf16(vfr[dt][g32], u.h, O[dt], 0, 0, 0);
    }
  }
  float inv = 1.f / lrun;
  #pragma unroll
  for (int dt = 0; dt < 4; dt++) {
    ushort4 o;
    unsigned short* op = (unsigned short*)&o;
    #pragma unroll
    for (int r = 0; r < 4; r++) op[r] = f2b(O[dt][r] * inv);
    *(ushort4*)&out[(size_t)(b * T + trow) * 1024 + h * 64 + dt * 16 + quad * 4] = o;
  }
}

// ---------- host ----------
extern "C" void kernel_launch(void* const* d_in, const int* in_sizes, int n_in,
                              void* d_out, int out_size, void* d_ws, size_t ws_size,
                              hipStream_t stream) {
  const int B = 2, T = 2048, C = 1024, H = 16, D = 64, FF = 4096;
  const int M = B * T;  // 4096
  const float* x   = (const float*)d_in[0];
  const float* Wq  = (const float*)d_in[1];
  const float* Wk  = (const float*)d_in[2];
  const float* Wv  = (const float*)d_in[3];
  const float* Wo  = (const float*)d_in[4];
  const float* bo  = (const float*)d_in[5];
  const float* W1  = (const float*)d_in[6];
  const float* b1  = (const float*)d_in[7];
  const float* W2  = (const float*)d_in[8];
  const float* b2  = (const float*)d_in[9];
  const float* g1  = (const float*)d_in[10];
  const float* be1 = (const float*)d_in[11];
  const float* g2  = (const float*)d_in[12];
  const float* be2 = (const float*)d_in[13];
  float* out = (float*)d_out;

  char* ws = (char*)d_ws;
  size_t off = 0;
  auto alloc = [&](size_t bytes) {
    void* p = ws + off;
    off += (bytes + 255) & ~(size_t)255;
    return p;
  };
  // NOTE: split-K partial buffers alias dead regions (layout-dependent!):
  //   pf0 = vtb (spans vtb+aout, dead after Wo gemm)  = M*C floats
  //   pf1 = qkvt (spans qkvt+wot+w1t, dead after ff1) = M*C floats
  ushort_t* qkvt = (ushort_t*)alloc((size_t)3 * C * C * 2);  // 6.29 MB
  ushort_t* wot  = (ushort_t*)alloc((size_t)C * C * 2);      // 2.10 MB
  ushort_t* w1t  = (ushort_t*)alloc((size_t)FF * C * 2);     // 8.39 MB
  ushort_t* w2t  = (ushort_t*)alloc((size_t)C * FF * 2);     // 8.39 MB
  ushort_t* hbuf = (ushort_t*)alloc((size_t)M * C * 2);      // 8.39 MB
  ushort_t* big  = (ushort_t*)alloc((size_t)M * FF * 2);     // 33.55 MB
  ushort_t* vtb  = (ushort_t*)alloc((size_t)M * C * 2);      // 8.39 MB
  ushort_t* aout = (ushort_t*)alloc((size_t)M * C * 2);      // 8.39 MB
  float*    x2   = (float*)alloc((size_t)M * C * 4);         // 16.78 MB
  float* pf0 = (float*)vtb;    // 16.78 MB span (vtb+aout)
  float* pf1 = (float*)qkvt;   // 16.78 MB span (qkvt+wot+w1t)

  dim3 tb(32, 8);
  transpose_cast_kernel<<<dim3(D / 32, C / 32, H), tb, 0, stream>>>(Wq, qkvt, C, D);
  transpose_cast_kernel<<<dim3(D / 32, C / 32, H), tb, 0, stream>>>(Wk, qkvt + (size_t)C * C, C, D);
  transpose_cast_kernel<<<dim3(D / 32, C / 32, H), tb, 0, stream>>>(Wv, qkvt + (size_t)2 * C * C, C, D);
  transpose_cast_kernel<<<dim3(C / 32, C / 32, 1), tb, 0, stream>>>(Wo, wot, C, C);
  transpose_cast_kernel<<<dim3(FF / 32, C / 32, 1), tb, 0, stream>>>(W1, w1t, C, FF);
  transpose_cast_kernel<<<dim3(C / 32, FF / 32, 1), tb, 0, stream>>>(W2, w2t, FF, C);
  ln_kernel<<<M, 256, 0, stream>>>(x, g1, be1, hbuf);
  // QKV = h @ Wqkv^T -> bf16  (768 blocks, 3/CU)
  gemm_bt_kernel<3072, 1024, 2, 1><<<dim3(24, 32), 256, 0, stream>>>(
      hbuf, qkvt, nullptr, nullptr, big, nullptr, nullptr);
  transpose_v_kernel<<<dim3(2, T / 32, B * H), tb, 0, stream>>>(big, vtb);
  attn_kernel<<<1024, 256, 0, stream>>>(big, vtb, aout);
  // x2 = attn @ Wo^T + bo + x (fp32)  (256 blocks)
  gemm_bt_kernel<1024, 1024, 4 | 8, 1><<<dim3(8, 32), 256, 0, stream>>>(
      aout, wot, bo, x, x2, nullptr, nullptr);
  ln_kernel<<<M, 256, 0, stream>>>(x2, g2, be2, hbuf);
  // ff1 = relu(h2 @ W1^T + b1) -> bf16  (1024 blocks, 4/CU)
  gemm_bt_kernel<4096, 1024, 1 | 2 | 4, 1><<<dim3(32, 32), 256, 0, stream>>>(
      hbuf, w1t, b1, nullptr, big, nullptr, nullptr);
  // ff2 split-K=2: partials (512 blocks, 2/CU), then reduce
  gemm_bt_kernel<1024, 4096, 0, 2><<<dim3(8, 32, 2), 256, 0, stream>>>(
      big, w2t, nullptr, nullptr, nullptr, pf0, pf1);
  reduce2_kernel<<<M * C / 1024, 256, 0, stream>>>(pf0, pf1, b2, x2, out);
}

// Round 10
// 365.730 us; speedup vs baseline: 1.0567x; 1.0416x over previous
//
#include <hip/hip_runtime.h>
#include <stdint.h>

typedef unsigned short ushort_t;
typedef __attribute__((ext_vector_type(8))) short bf16x8;   // 8 bf16 in 4 VGPRs
typedef __attribute__((ext_vector_type(4))) float f32x4;

// ---------- helpers ----------
__device__ __forceinline__ unsigned short f2b(float f) {
  unsigned u = __float_as_uint(f);
  u += 0x7fffu + ((u >> 16) & 1u);   // round-to-nearest-even
  return (unsigned short)(u >> 16);
}

__device__ __forceinline__ void async16(const void* g, void* l) {
  __builtin_amdgcn_global_load_lds(
      (const __attribute__((address_space(1))) void*)g,
      (__attribute__((address_space(3))) void*)l, 16, 0, 0);
}

// ---------- LayerNorm (fp32 in -> bf16 out), one block per row, C=1024 ----------
__global__ __launch_bounds__(256) void ln_kernel(
    const float* __restrict__ x, const float* __restrict__ g,
    const float* __restrict__ be, ushort_t* __restrict__ out) {
  const int C = 1024;
  int row = blockIdx.x;
  const float4* xr = (const float4*)(x + (size_t)row * C);
  int tid = threadIdx.x;
  float4 v = xr[tid];
  float s = v.x + v.y + v.z + v.w;
  float sq = v.x * v.x + v.y * v.y + v.z * v.z + v.w * v.w;
  #pragma unroll
  for (int off = 32; off > 0; off >>= 1) {
    s += __shfl_xor(s, off);
    sq += __shfl_xor(sq, off);
  }
  __shared__ float ss[4], ssq[4];
  int wv = tid >> 6;
  if ((tid & 63) == 0) { ss[wv] = s; ssq[wv] = sq; }
  __syncthreads();
  s = ss[0] + ss[1] + ss[2] + ss[3];
  sq = ssq[0] + ssq[1] + ssq[2] + ssq[3];
  float mu = s * (1.f / C);
  float var = sq * (1.f / C) - mu * mu;
  float rs = rsqrtf(var + 1e-5f);
  float4 gv = ((const float4*)g)[tid];
  float4 bv = ((const float4*)be)[tid];
  ushort4 o;
  o.x = f2b((v.x - mu) * rs * gv.x + bv.x);
  o.y = f2b((v.y - mu) * rs * gv.y + bv.y);
  o.z = f2b((v.z - mu) * rs * gv.z + bv.z);
  o.w = f2b((v.w - mu) * rs * gv.w + bv.w);
  ((ushort4*)(out + (size_t)row * C))[tid] = o;
}

// ---------- split-K final reduce: out = p0 + p1 + bias + resid (fp32), N=1024 ----------
__global__ __launch_bounds__(256) void reduce2_kernel(
    const float* __restrict__ p0, const float* __restrict__ p1,
    const float* __restrict__ bias, const float* __restrict__ resid,
    float* __restrict__ out) {
  int idx = blockIdx.x * 256 + threadIdx.x;      // float4 index
  float4 a = ((const float4*)p0)[idx];
  float4 b = ((const float4*)p1)[idx];
  float4 r = ((const float4*)resid)[idx];
  float4 bi = ((const float4*)bias)[idx & 255];  // 1024 floats = 256 float4 per row
  float4 o;
  o.x = a.x + b.x + r.x + bi.x;
  o.y = a.y + b.y + r.y + bi.y;
  o.z = a.z + b.z + r.z + bi.z;
  o.w = a.w + b.w + r.w + bi.w;
  ((float4*)out)[idx] = o;
}

// ---------- batched transpose + fp32->bf16 cast: in (bz,R,Cin) -> out (bz,Cin,R) ----------
__global__ __launch_bounds__(256) void transpose_cast_kernel(
    const float* __restrict__ in, ushort_t* __restrict__ out, int R, int Cin) {
  __shared__ float tile[32][33];
  int bz = blockIdx.z;
  in += (size_t)bz * R * Cin;
  out += (size_t)bz * R * Cin;
  int c0 = blockIdx.x * 32, r0 = blockIdx.y * 32;
  int tx = threadIdx.x, ty = threadIdx.y;
  #pragma unroll
  for (int i = 0; i < 4; i++)
    tile[ty + 8 * i][tx] = in[(size_t)(r0 + ty + 8 * i) * Cin + c0 + tx];
  __syncthreads();
  #pragma unroll
  for (int i = 0; i < 4; i++)
    out[(size_t)(c0 + ty + 8 * i) * R + r0 + tx] = f2b(tile[tx][ty + 8 * i]);
}

// ---------- V transpose: QKV (4096,3072) bf16 -> Vt (B*H, 64, 2048) bf16 ----------
__global__ __launch_bounds__(256) void transpose_v_kernel(
    const ushort_t* __restrict__ qkv, ushort_t* __restrict__ vt) {
  __shared__ ushort_t tile[32][33];
  int bh = blockIdx.z;
  int b = bh >> 4, h = bh & 15;
  int d0 = blockIdx.x * 32, t0 = blockIdx.y * 32;
  int tx = threadIdx.x, ty = threadIdx.y;
  #pragma unroll
  for (int i = 0; i < 4; i++)
    tile[ty + 8 * i][tx] =
        qkv[(size_t)(b * 2048 + t0 + ty + 8 * i) * 3072 + 2048 + h * 64 + d0 + tx];
  __syncthreads();
  #pragma unroll
  for (int i = 0; i < 4; i++)
    vt[(size_t)(bh * 64 + d0 + ty + 8 * i) * 2048 + t0 + tx] = tile[tx][ty + 8 * i];
}

// ---------- GEMM: out(M,N) = A(M,K) @ Bt(N,K)^T, bf16 in, 128x128 tile, dbuf ----------
// 1D grid of BN*32*SK blocks with XCD-group swizzle: the 8 bn-tiles sharing an
// A-row-block get block ids congruent mod 8 -> same XCD -> A fetched once per
// XCD L2 instead of 8x from HBM. FLAGS: 1=relu, 2=bf16 out, 4=+bias, 8=+resid.
template <int BN, int N, int K, int FLAGS, int SK>
__global__ __launch_bounds__(256, 3) void gemm_bt_kernel(
    const ushort_t* __restrict__ A, const ushort_t* __restrict__ Bt,
    const float* __restrict__ bias, const float* __restrict__ resid,
    void* __restrict__ outv, float* __restrict__ pp0, float* __restrict__ pp1) {
  constexpr int KS = K / SK;             // K-span per block
  __shared__ ushort_t Als[2][128 * 32];
  __shared__ ushort_t Bls[2][128 * 32];
  int tid = threadIdx.x, w = tid >> 6, lane = tid & 63, quad = lane >> 4, l16 = lane & 15;
  // ---- XCD-group swizzle (fid mod 8 = XCD under round-robin dispatch) ----
  int fid = blockIdx.x;
  int bn_low = (fid >> 3) & 7;
  int meta = (fid & 7) | ((fid >> 6) << 3);
  int bm = meta & 31;                    // BM = 32 always (M = 4096)
  int high = meta >> 5;
  int bn, zz;
  if constexpr (SK > 1) { zz = high; bn = bn_low; }
  else { zz = 0; bn = bn_low + 8 * high; }
  int bn0 = bn * 128, bm0 = bm * 128;
  int koff = (SK > 1) ? zz * KS : 0;
  int wm = (w >> 1) * 64, wn = (w & 1) * 64;
  f32x4 acc[4][4];
  #pragma unroll
  for (int i = 0; i < 4; i++)
    #pragma unroll
    for (int j = 0; j < 4; j++) acc[i][j] = f32x4{0.f, 0.f, 0.f, 0.f};
  const ushort_t* Ag = A + (size_t)bm0 * K + koff;
  const ushort_t* Bg = Bt + (size_t)bn0 * K + koff;
  int lr = lane >> 2, lco = (lane & 3) * 8;
  auto stage = [&](int k0, int bi) {
    async16(Ag + (size_t)(w * 32 + lr) * K + k0 + lco, &Als[bi][w * 1024]);
    async16(Ag + (size_t)(w * 32 + 16 + lr) * K + k0 + lco, &Als[bi][w * 1024 + 512]);
    async16(Bg + (size_t)(w * 32 + lr) * K + k0 + lco, &Bls[bi][w * 1024]);
    async16(Bg + (size_t)(w * 32 + 16 + lr) * K + k0 + lco, &Bls[bi][w * 1024 + 512]);
  };
  stage(0, 0);
  int s = 0;
  for (int k0 = 0; k0 < KS; k0 += 32, s ^= 1) {
    __syncthreads();
    if (k0 + 32 < KS) stage(k0 + 32, s ^ 1);
    bf16x8 af[4], bf[4];
    #pragma unroll
    for (int i = 0; i < 4; i++)
      af[i] = *(const bf16x8*)&Als[s][(wm + i * 16 + l16) * 32 + quad * 8];
    #pragma unroll
    for (int j = 0; j < 4; j++)
      bf[j] = *(const bf16x8*)&Bls[s][(wn + j * 16 + l16) * 32 + quad * 8];
    #pragma unroll
    for (int i = 0; i < 4; i++)
      #pragma unroll
      for (int j = 0; j < 4; j++)
        acc[i][j] = __builtin_amdgcn_mfma_f32_16x16x32_bf16(af[i], bf[j], acc[i][j], 0, 0, 0);
  }
  float* pdst = nullptr;
  if constexpr (SK > 1) pdst = zz ? pp1 : pp0;
  #pragma unroll
  for (int i = 0; i < 4; i++)
    #pragma unroll
    for (int j = 0; j < 4; j++)
      #pragma unroll
      for (int r = 0; r < 4; r++) {
        int row = bm0 + wm + i * 16 + quad * 4 + r;
        int col = bn0 + wn + j * 16 + l16;
        float v = acc[i][j][r];
        if constexpr (SK > 1) {
          pdst[(size_t)row * N + col] = v;   // raw partial
        } else {
          if constexpr (FLAGS & 4) v += bias[col];
          if constexpr (FLAGS & 8) v += resid[(size_t)row * N + col];
          if constexpr (FLAGS & 1) v = fmaxf(v, 0.f);
          if constexpr ((FLAGS & 2) != 0)
            ((ushort_t*)outv)[(size_t)row * N + col] = f2b(v);
          else
            ((float*)outv)[(size_t)row * N + col] = v;
        }
      }
}

// ---------- causal flash attention: dbuf LDS staging + S^T softmax ----------
// 1024 blocks = 32 (b,h) x 32 q-blocks of 64 rows -> 4 blocks/CU.
__global__ __launch_bounds__(256, 4) void attn_kernel(
    const ushort_t* __restrict__ qkv, const ushort_t* __restrict__ vt,
    ushort_t* __restrict__ out) {
  const int T = 2048, CC = 3072;
  __shared__ ushort_t Kls[2][2 * 64 * 32];
  __shared__ ushort_t Vls[2][2 * 64 * 32];
  int fid = blockIdx.x;                       // 1024
  int bh = (fid & 7) * 4 + ((fid >> 3) & 3);  // XCD swizzle: 4 heads per XCD
  int qb = 31 - (fid >> 5);                   // longest q-blocks first
  int b = bh >> 4, h = bh & 15;
  int q0 = qb * 64;
  int tid = threadIdx.x, w = tid >> 6, lane = tid & 63, quad = lane >> 4, l16 = lane & 15;
  int srow = w * 16 + (lane >> 2);
  int sco = (lane & 3) * 8;
  const ushort_t* kg = qkv + (size_t)(b * T + srow) * CC + 1024 + h * 64 + sco;
  const ushort_t* vg = vt + (size_t)(bh * 64 + srow) * T + sco;
  int q0s = q0 + w * 16;
  int trow = q0s + l16;
  const ushort_t* qp = qkv + (size_t)(b * T + trow) * CC + h * 64 + quad * 8;
  bf16x8 aq[2] = { *(const bf16x8*)qp, *(const bf16x8*)(qp + 32) };
  f32x4 O[4];
  #pragma unroll
  for (int i = 0; i < 4; i++) O[i] = f32x4{0.f, 0.f, 0.f, 0.f};
  float mrun = -1e30f, lrun = 0.f;
  const float ksc = 0.03125f * 1.44269504f;  // C^-0.5 * log2(e)
  int src0 = (quad & 1) * 32 + l16;
  int src1 = src0 + 16;
  bool hiq = quad >= 2;
  auto stage = [&](int kb, int bi) {
    int s0 = kb * 64;
    async16(kg + (size_t)s0 * CC, &Kls[bi][w * 512]);
    async16(kg + (size_t)s0 * CC + 32, &Kls[bi][2048 + w * 512]);
    async16(vg + s0, &Vls[bi][w * 512]);
    async16(vg + s0 + 32, &Vls[bi][2048 + w * 512]);
  };
  stage(0, 0);
  for (int kb = 0; kb <= qb; kb++) {
    __syncthreads();
    if (kb < qb) stage(kb + 1, (kb + 1) & 1);
    int bi = kb & 1;
    int s0 = kb * 64;
    bf16x8 kfr[4][2], vfr[4][2];
    #pragma unroll
    for (int t = 0; t < 4; t++)
      #pragma unroll
      for (int ks = 0; ks < 2; ks++) {
        kfr[t][ks] = *(const bf16x8*)&Kls[bi][(ks * 64 + t * 16 + l16) * 32 + quad * 8];
        vfr[t][ks] = *(const bf16x8*)&Vls[bi][(ks * 64 + t * 16 + l16) * 32 + quad * 8];
      }
    f32x4 st[4];
    #pragma unroll
    for (int t = 0; t < 4; t++) {
      st[t] = f32x4{0.f, 0.f, 0.f, 0.f};
      #pragma unroll
      for (int ks = 0; ks < 2; ks++)
        st[t] = __builtin_amdgcn_mfma_f32_16x16x32_bf16(kfr[t][ks], aq[ks], st[t], 0, 0, 0);
    }
    float sv[4][4];
    float vmax = -1e30f;
    if (kb == qb) {
      #pragma unroll
      for (int t = 0; t < 4; t++)
        #pragma unroll
        for (int r = 0; r < 4; r++) {
          float sc = st[t][r] * ksc;
          int scol = s0 + t * 16 + quad * 4 + r;
          if (scol > trow) sc = -1e30f;
          sv[t][r] = sc;
          vmax = fmaxf(vmax, sc);
        }
    } else {
      #pragma unroll
      for (int t = 0; t < 4; t++)
        #pragma unroll
        for (int r = 0; r < 4; r++) {
          float sc = st[t][r] * ksc;
          sv[t][r] = sc;
          vmax = fmaxf(vmax, sc);
        }
    }
    vmax = fmaxf(vmax, __shfl_xor(vmax, 16));
    vmax = fmaxf(vmax, __shfl_xor(vmax, 32));
    float mnew = fmaxf(mrun, vmax);
    float alpha = __builtin_amdgcn_exp2f(mrun - mnew);
    mrun = mnew;
    float psum = 0.f;
    int pk[4][2];
    #pragma unroll
    for (int t = 0; t < 4; t++) {
      float p0 = __builtin_amdgcn_exp2f(sv[t][0] - mnew);
      float p1 = __builtin_amdgcn_exp2f(sv[t][1] - mnew);
      float p2 = __builtin_amdgcn_exp2f(sv[t][2] - mnew);
      float p3 = __builtin_amdgcn_exp2f(sv[t][3] - mnew);
      psum += (p0 + p1) + (p2 + p3);
      pk[t][0] = (int)((unsigned)f2b(p0) | ((unsigned)f2b(p1) << 16));
      pk[t][1] = (int)((unsigned)f2b(p2) | ((unsigned)f2b(p3) << 16));
    }
    psum += __shfl_xor(psum, 16);
    psum += __shfl_xor(psum, 32);
    lrun = lrun * alpha + psum;
    #pragma unroll
    for (int dt = 0; dt < 4; dt++) O[dt] *= alpha;
    #pragma unroll
    for (int g32 = 0; g32 < 2; g32++) {
      int t0 = 2 * g32, t1 = t0 + 1;
      int a0 = __shfl(pk[t0][0], src0), b0 = __shfl(pk[t1][0], src0);
      int a1 = __shfl(pk[t0][1], src0), b1 = __shfl(pk[t1][1], src0);
      int a2 = __shfl(pk[t0][0], src1), b2 = __shfl(pk[t1][0], src1);
      int a3 = __shfl(pk[t0][1], src1), b3 = __shfl(pk[t1][1], src1);
      union { int4 i; bf16x8 h; } u;
      u.i.x = hiq ? b0 : a0;
      u.i.y = hiq ? b1 : a1;
      u.i.z = hiq ? b2 : a2;
      u.i.w = hiq ? b3 : a3;
      #pragma unroll
      for (int dt = 0; dt < 4; dt++)
        O[dt] = __builtin_amdgcn_mfma_f32_16x16x32_bf16(vfr[dt][g32], u.h, O[dt], 0, 0, 0);
    }
  }
  float inv = 1.f / lrun;
  #pragma unroll
  for (int dt = 0; dt < 4; dt++) {
    ushort4 o;
    unsigned short* op = (unsigned short*)&o;
    #pragma unroll
    for (int r = 0; r < 4; r++) op[r] = f2b(O[dt][r] * inv);
    *(ushort4*)&out[(size_t)(b * T + trow) * 1024 + h * 64 + dt * 16 + quad * 4] = o;
  }
}

// ---------- host ----------
extern "C" void kernel_launch(void* const* d_in, const int* in_sizes, int n_in,
                              void* d_out, int out_size, void* d_ws, size_t ws_size,
                              hipStream_t stream) {
  const int B = 2, T = 2048, C = 1024, H = 16, D = 64, FF = 4096;
  const int M = B * T;  // 4096
  const float* x   = (const float*)d_in[0];
  const float* Wq  = (const float*)d_in[1];
  const float* Wk  = (const float*)d_in[2];
  const float* Wv  = (const float*)d_in[3];
  const float* Wo  = (const float*)d_in[4];
  const float* bo  = (const float*)d_in[5];
  const float* W1  = (const float*)d_in[6];
  const float* b1  = (const float*)d_in[7];
  const float* W2  = (const float*)d_in[8];
  const float* b2  = (const float*)d_in[9];
  const float* g1  = (const float*)d_in[10];
  const float* be1 = (const float*)d_in[11];
  const float* g2  = (const float*)d_in[12];
  const float* be2 = (const float*)d_in[13];
  float* out = (float*)d_out;

  char* ws = (char*)d_ws;
  size_t off = 0;
  auto alloc = [&](size_t bytes) {
    void* p = ws + off;
    off += (bytes + 255) & ~(size_t)255;
    return p;
  };
  // NOTE: split-K partial buffers alias dead regions (layout-dependent!):
  //   pf0 = vtb (spans vtb+aout, dead after Wo gemm)  = M*C floats
  //   pf1 = qkvt (spans qkvt+wot+w1t, dead after ff1) = M*C floats
  ushort_t* qkvt = (ushort_t*)alloc((size_t)3 * C * C * 2);  // 6.29 MB
  ushort_t* wot  = (ushort_t*)alloc((size_t)C * C * 2);      // 2.10 MB
  ushort_t* w1t  = (ushort_t*)alloc((size_t)FF * C * 2);     // 8.39 MB
  ushort_t* w2t  = (ushort_t*)alloc((size_t)C * FF * 2);     // 8.39 MB
  ushort_t* hbuf = (ushort_t*)alloc((size_t)M * C * 2);      // 8.39 MB
  ushort_t* big  = (ushort_t*)alloc((size_t)M * FF * 2);     // 33.55 MB
  ushort_t* vtb  = (ushort_t*)alloc((size_t)M * C * 2);      // 8.39 MB
  ushort_t* aout = (ushort_t*)alloc((size_t)M * C * 2);      // 8.39 MB
  float*    x2   = (float*)alloc((size_t)M * C * 4);         // 16.78 MB
  float* pf0 = (float*)vtb;    // 16.78 MB span (vtb+aout)
  float* pf1 = (float*)qkvt;   // 16.78 MB span (qkvt+wot+w1t)

  dim3 tb(32, 8);
  transpose_cast_kernel<<<dim3(D / 32, C / 32, H), tb, 0, stream>>>(Wq, qkvt, C, D);
  transpose_cast_kernel<<<dim3(D / 32, C / 32, H), tb, 0, stream>>>(Wk, qkvt + (size_t)C * C, C, D);
  transpose_cast_kernel<<<dim3(D / 32, C / 32, H), tb, 0, stream>>>(Wv, qkvt + (size_t)2 * C * C, C, D);
  transpose_cast_kernel<<<dim3(C / 32, C / 32, 1), tb, 0, stream>>>(Wo, wot, C, C);
  transpose_cast_kernel<<<dim3(FF / 32, C / 32, 1), tb, 0, stream>>>(W1, w1t, C, FF);
  transpose_cast_kernel<<<dim3(C / 32, FF / 32, 1), tb, 0, stream>>>(W2, w2t, FF, C);
  ln_kernel<<<M, 256, 0, stream>>>(x, g1, be1, hbuf);
  // QKV = h @ Wqkv^T -> bf16  (768 blocks, XCD-grouped)
  gemm_bt_kernel<24, 3072, 1024, 2, 1><<<768, 256, 0, stream>>>(
      hbuf, qkvt, nullptr, nullptr, big, nullptr, nullptr);
  transpose_v_kernel<<<dim3(2, T / 32, B * H), tb, 0, stream>>>(big, vtb);
  attn_kernel<<<1024, 256, 0, stream>>>(big, vtb, aout);
  // x2 = attn @ Wo^T + bo + x (fp32)  (256 blocks, XCD-grouped)
  gemm_bt_kernel<8, 1024, 1024, 4 | 8, 1><<<256, 256, 0, stream>>>(
      aout, wot, bo, x, x2, nullptr, nullptr);
  ln_kernel<<<M, 256, 0, stream>>>(x2, g2, be2, hbuf);
  // ff1 = relu(h2 @ W1^T + b1) -> bf16  (1024 blocks, XCD-grouped)
  gemm_bt_kernel<32, 4096, 1024, 1 | 2 | 4, 1><<<1024, 256, 0, stream>>>(
      hbuf, w1t, b1, nullptr, big, nullptr, nullptr);
  // ff2 split-K=2: partials (512 blocks, XCD-grouped), then reduce
  gemm_bt_kernel<8, 1024, 4096, 0, 2><<<512, 256, 0, stream>>>(
      big, w2t, nullptr, nullptr, nullptr, pf0, pf1);
  reduce2_kernel<<<M * C / 1024, 256, 0, stream>>>(pf0, pf1, b2, x2, out);
}